// Round 12
// baseline (2803.627 us; speedup 1.0000x reference)
//
#include <hip/hip_runtime.h>
#include <hip/hip_bf16.h>

// ScalarBorn: 4th-order FD scalar wave + Born scattering with CPML, MI355X.
// R26 = R25 (2078us best) with INTERIOR 6-ROW BLOCKS: 198 interior rows =
// 6 x 33 exactly; thread owns rows y0..y0+5, shared 10-row w window
// (1.67 w-loads/row; interior loads/row 3.67 vs 4.33 float4, -15%).
// Frame path byte-identical. Grid 456 blocks (8 x (24 frame + 33 int6)),
// 1.78/CU -> bounds(256,2): cap 256 (no spill risk for the 40-reg window),
// residency 2/CU guaranteed, one dispatch round. ILP (6 independent rows,
// ~22 in-flight loads/thread) substitutes for the reduced TLP (R25 evidence:
// 2.8 waves/SIMD already sufficient).
// Kept: XCD banding (R15 -33%), one-round (R18), shuffle x-exchange / no LDS
// / no barriers (R19), interior row-merge traffic cut (R23 -9%, R25 -2%).
// Falsified: 2-row frame merge (R24 +9%), 512-thr 2-row cap64 (R22 +19%),
// direct-load x-exch (R21 +54%), declustering (R20 +5%), full hoist (R16
// +19%), cheap hoist (R17 +5%), aggregation (R8/R10), barrier removal w/
// LDS (R12/R13), load cuts (R7), grid.sync (R4).

constexpr int NYX  = 400;
constexpr int NS   = 4;
constexpr int NREC = 100;
constexpr int NT   = 300;
constexpr int PAD  = 22;
constexpr int NP   = 444;
constexpr int NP2  = NP * NP;          // 197136
constexpr int SNP2 = NS * NP2;         // 788544
constexpr int NBLK = 456;              // 8 half-bands x (24 frame + 33 int6)
constexpr float DT    = 0.0005f;
constexpr float INVH  = 0.2f;
constexpr float INVH2 = 0.04f;
constexpr float C1A = 1.0f / 12.0f;
constexpr float C1B = 2.0f / 3.0f;
constexpr float C2A = -1.0f / 12.0f;
constexpr float C2B = 4.0f / 3.0f;
constexpr float C2C = -2.5f;

// interleaved state: element (b,s) pair for grid index idx lives at [2*idx, 2*idx+1]
__device__ __align__(16) float g_w[2][2 * SNP2];   // wavefield ping-pong
__device__ __align__(16) float g_px[2][2 * SNP2];  // psi_x dbuf
__device__ __align__(16) float g_py[2][2 * SNP2];  // psi_y dbuf
__device__ __align__(16) float g_zx[2 * SNP2];     // zeta_x
__device__ __align__(16) float g_zy[2 * SNP2];     // zeta_y
__device__ __align__(16) float g_vb[2 * NP2];      // (v2dt2, bscale) pairs
__device__ float g_pa[NP];
__device__ float g_pb[NP];
__device__ float g_fbg[NT * NS];
__device__ float g_fsc[NT * NS];
__device__ int   g_spos[2 * NS];
__device__ int   g_mode;               // 1 = bf16 io, 0 = f32 io

__device__ __forceinline__ int clampi(int v, int lo, int hi) {
    return v < lo ? lo : (v > hi ? hi : v);
}
__device__ __forceinline__ float in_ld(const void* p, int i) {
    if (g_mode) return __bfloat162float(((const __hip_bfloat16*)p)[i]);
    return ((const float*)p)[i];
}
__device__ __forceinline__ void out_st(void* p, int i, float v) {
    if (g_mode) ((__hip_bfloat16*)p)[i] = __float2bfloat16(v);
    else        ((float*)p)[i] = v;
}
// float4 = (b0,s0,b1,s1) at row yy, col pair ip of shot s; 0 if row OOB
__device__ __forceinline__ float4 ld4(const float* w, int s, int yy, int ip) {
    if ((unsigned)yy >= (unsigned)NP) return make_float4(0.f, 0.f, 0.f, 0.f);
    return *(const float4*)(w + 2 * (s * NP2 + yy * NP + 2 * ip));
}
__device__ __forceinline__ float4 shup4(float4 v) {
    return make_float4(__shfl_up(v.x, 1), __shfl_up(v.y, 1),
                       __shfl_up(v.z, 1), __shfl_up(v.w, 1));
}
__device__ __forceinline__ float4 shdn4(float4 v) {
    return make_float4(__shfl_down(v.x, 1), __shfl_down(v.y, 1),
                       __shfl_down(v.z, 1), __shfl_down(v.w, 1));
}

__global__ void detect_mode(const void* vptr) {
    if (threadIdx.x == 0 && blockIdx.x == 0) {
        const __hip_bfloat16* p = (const __hip_bfloat16*)vptr;
        int ok = 1;
        for (int i = 0; i < 32; i += 2) {
            float f = __bfloat162float(p[i]);
            if (!(f >= 1000.f && f <= 3000.f)) ok = 0;
        }
        g_mode = ok;
    }
}

__global__ void zero_state() {
    int i = blockIdx.x * blockDim.x + threadIdx.x;
    if (i >= SNP2 / 2) return;           // each array = 2*SNP2 floats = SNP2/2 float4
    float4 z = make_float4(0.f, 0.f, 0.f, 0.f);
    ((float4*)g_w[0])[i] = z;  ((float4*)g_w[1])[i] = z;
    ((float4*)g_px[0])[i] = z; ((float4*)g_px[1])[i] = z;
    ((float4*)g_py[0])[i] = z; ((float4*)g_py[1])[i] = z;
    ((float4*)g_zx)[i] = z;    ((float4*)g_zy)[i] = z;
}

__global__ void prep_pad(const void* __restrict__ v, const void* __restrict__ sc) {
    int i = blockIdx.x * blockDim.x + threadIdx.x;
    if (i >= NP2) return;
    int y = i / NP, x = i % NP;
    int vy = clampi(y - PAD, 0, NYX - 1);
    int vx = clampi(x - PAD, 0, NYX - 1);
    float vv = in_ld(v, vy * NYX + vx);
    float vd = vv * DT;
    float s = 0.f;
    if (y >= PAD && y < PAD + NYX && x >= PAD && x < PAD + NYX)
        s = in_ld(sc, (y - PAD) * NYX + (x - PAD));
    g_vb[2 * i]     = vd * vd;
    g_vb[2 * i + 1] = 2.f * vv * s * DT * DT;
    if (i < NP) {
        float fi = (float)i;
        float f1 = fminf(fmaxf((22.f - fi) * 0.05f, 0.f), 1.f);
        float f2 = fminf(fmaxf((fi - 421.f) * 0.05f, 0.f), 1.f);
        float frac = fmaxf(f1, f2);
        float sigma = 259.0408229f * frac * frac;
        const float alpha = 78.53981634f;
        float a = expf(-(sigma + alpha) * DT);
        g_pa[i] = a;
        g_pb[i] = (sigma > 0.f) ? sigma / (sigma + alpha) * (a - 1.f) : 0.f;
    }
}

__global__ void prep_src(const void* __restrict__ amp, const int* __restrict__ sloc,
                         const void* __restrict__ v, const void* __restrict__ sc) {
    int i = blockIdx.x * blockDim.x + threadIdx.x;
    if (i >= NT * NS) return;
    int s = i % NS, t = i / NS;
    int ly = clampi(sloc[s * 2 + 0], 0, NYX - 1);
    int lx = clampi(sloc[s * 2 + 1], 0, NYX - 1);
    float a  = in_ld(amp, s * NT + t);
    float vv = in_ld(v,  ly * NYX + lx);
    float ss = in_ld(sc, ly * NYX + lx);
    g_fbg[i] = -a * vv * vv * DT * DT;
    g_fsc[i] = -2.f * a * vv * ss * DT * DT;
    if (i < NS) {
        g_spos[2 * i]     = ly + PAD;
        g_spos[2 * i + 1] = lx + PAD;
    }
}

// Interior-row update (pb[y]==0 guaranteed: no psi_y/zeta_y/dpy).
// All lanes must call (shuffles inside); halo lanes exit after shuffles.
__device__ __forceinline__ void row_interior(
    int t, int s, int y, int ip, bool inb, bool owner, bool pxreg,
    float pbx0, float pbx1, float pax0, float pax1,
    float4 ym2, float4 ym1, float4 w4, float4 yp1, float4 yp2,
    int cur, int nxt)
{
    const int x0 = 2 * ip, x1 = x0 + 1;
    const int yx  = y * NP + x0;
    const int idx = s * NP2 + yx;
    const float4 z4 = make_float4(0.f, 0.f, 0.f, 0.f);

    float4 wl = shup4(w4);         // pair ip-1
    float4 wr = shdn4(w4);         // pair ip+1

    float d2x_b0 = 0.f, d2x_s0 = 0.f, d2x_b1 = 0.f, d2x_s1 = 0.f;
    float4 pxn = z4;
    if (inb) {
        d2x_b0 = (C2A * (wl.x + wr.x) + C2B * (wl.z + w4.z) + C2C * w4.x) * INVH2;
        d2x_s0 = (C2A * (wl.y + wr.y) + C2B * (wl.w + w4.w) + C2C * w4.y) * INVH2;
        d2x_b1 = (C2A * (wl.z + wr.z) + C2B * (w4.x + wr.x) + C2C * w4.z) * INVH2;
        d2x_s1 = (C2A * (wl.w + wr.w) + C2B * (w4.y + wr.y) + C2C * w4.w) * INVH2;
        if (pxreg && pbx0 != 0.f) {      // pb pair-uniform
            float4 pxo = *(const float4*)(g_px[cur] + 2 * idx);
            float dwb0 = (C1A * wl.x - C1B * wl.z + C1B * w4.z - C1A * wr.x) * INVH;
            float dws0 = (C1A * wl.y - C1B * wl.w + C1B * w4.w - C1A * wr.y) * INVH;
            float dwb1 = (C1A * wl.z - C1B * w4.x + C1B * wr.x - C1A * wr.z) * INVH;
            float dws1 = (C1A * wl.w - C1B * w4.y + C1B * wr.y - C1A * wr.w) * INVH;
            pxn.x = pax0 * pxo.x + pbx0 * dwb0;
            pxn.y = pax0 * pxo.y + pbx0 * dws0;
            pxn.z = pax1 * pxo.z + pbx1 * dwb1;
            pxn.w = pax1 * pxo.w + pbx1 * dws1;
            if (owner)
                *(float4*)(g_px[nxt] + 2 * idx) = pxn;
        }
    }

    float dpx_b0 = 0.f, dpx_s0 = 0.f, dpx_b1 = 0.f, dpx_s1 = 0.f;
    {
        float4 pl = shup4(pxn);
        float4 pr = shdn4(pxn);
        if (pxreg) {
            dpx_b0 = (C1A * pl.x - C1B * pl.z + C1B * pxn.z - C1A * pr.x) * INVH;
            dpx_s0 = (C1A * pl.y - C1B * pl.w + C1B * pxn.w - C1A * pr.y) * INVH;
            dpx_b1 = (C1A * pl.z - C1B * pxn.x + C1B * pr.x - C1A * pr.z) * INVH;
            dpx_s1 = (C1A * pl.w - C1B * pxn.y + C1B * pr.y - C1A * pr.w) * INVH;
        }
    }
    if (!owner) return;

    float d2y_b0 = (C2A * (ym2.x + yp2.x) + C2B * (ym1.x + yp1.x) + C2C * w4.x) * INVH2;
    float d2y_s0 = (C2A * (ym2.y + yp2.y) + C2B * (ym1.y + yp1.y) + C2C * w4.y) * INVH2;
    float d2y_b1 = (C2A * (ym2.z + yp2.z) + C2B * (ym1.z + yp1.z) + C2C * w4.z) * INVH2;
    float d2y_s1 = (C2A * (ym2.w + yp2.w) + C2B * (ym1.w + yp1.w) + C2C * w4.w) * INVH2;

    float zx_b0 = 0.f, zx_s0 = 0.f, zx_b1 = 0.f, zx_s1 = 0.f;
    if (pbx0 != 0.f) {
        float4 zo = *(const float4*)(g_zx + 2 * idx);
        zx_b0 = pax0 * zo.x + pbx0 * (d2x_b0 + dpx_b0);
        zx_s0 = pax0 * zo.y + pbx0 * (d2x_s0 + dpx_s0);
        zx_b1 = pax1 * zo.z + pbx1 * (d2x_b1 + dpx_b1);
        zx_s1 = pax1 * zo.w + pbx1 * (d2x_s1 + dpx_s1);
        *(float4*)(g_zx + 2 * idx) = make_float4(zx_b0, zx_s0, zx_b1, zx_s1);
    }

    float4 vb   = *(const float4*)(g_vb + 2 * yx);
    float4 prev = *(const float4*)(g_w[nxt] + 2 * idx);
    float lap_b0 = d2y_b0 + d2x_b0 + dpx_b0 + zx_b0;
    float lap_s0 = d2y_s0 + d2x_s0 + dpx_s0 + zx_s0;
    float lap_b1 = d2y_b1 + d2x_b1 + dpx_b1 + zx_b1;
    float lap_s1 = d2y_s1 + d2x_s1 + dpx_s1 + zx_s1;
    float wn_b0 = vb.x * lap_b0 + 2.f * w4.x - prev.x;
    float wn_s0 = vb.x * lap_s0 + 2.f * w4.y - prev.y + vb.y * lap_b0;
    float wn_b1 = vb.z * lap_b1 + 2.f * w4.z - prev.z;
    float wn_s1 = vb.z * lap_s1 + 2.f * w4.w - prev.w + vb.w * lap_b1;
    if (y == g_spos[2 * s]) {
        int sx = g_spos[2 * s + 1];
        if (sx == x0)      { wn_b0 += g_fbg[t * NS + s]; wn_s0 += g_fsc[t * NS + s]; }
        else if (sx == x1) { wn_b1 += g_fbg[t * NS + s]; wn_s1 += g_fsc[t * NS + s]; }
    }
    *(float4*)(g_w[nxt] + 2 * idx) = make_float4(wn_b0, wn_s0, wn_b1, wn_s1);
}

// one fused timestep. 456 blocks, 256 threads. Block map: xcd = bid&7 owns a
// 222-row half-band of shot s = xcd>>1 (half = xcd&1); k = bid>>3 in [0,57):
//   k < 24  -> FRAME block, one row y = half ? 420+k : k      (R23/R19 body)
//   k >= 24 -> INTERIOR block, rows y0..y0+5; y0 = (half?222:24)+6*(k-24)
// Within a row, R19 layout: wave w lane l -> pair ip = 60w+l-2, owners [2,62).
// Barrier-free, LDS-free; x-exchange via shuffles. bounds(256,2): cap 256
// (no spills), 2 blocks/CU >= 1.78 needed -> one dispatch round.
__global__ void __launch_bounds__(256, 2)
step_fused(int t, const int* __restrict__ rloc, const int* __restrict__ rbloc,
           void* __restrict__ out) {
    const int i = threadIdx.x;
    const int bid = blockIdx.x;
    const int xcd = bid & 7;
    const int s = xcd >> 1;
    const int half = xcd & 1;
    const int k = bid >> 3;
    const int cur = t & 1, nxt = cur ^ 1;
    const bool isframe = (k < 24);
    const int y0 = isframe ? (half ? 420 + k : k)
                           : ((half ? 222 : 24) + 6 * (k - 24));

    if (t > 0 && isframe && y0 == 0 && i < 2 * NREC) {   // record step t-1
        int r = i % NREC;
        bool isbg = i < NREC;
        const int* rl = isbg ? rbloc : rloc;
        int ry = clampi(rl[(s * NREC + r) * 2 + 0], 0, NYX - 1) + PAD;
        int rx = clampi(rl[(s * NREC + r) * 2 + 1], 0, NYX - 1) + PAD;
        float val = g_w[cur][2 * (s * NP2 + ry * NP + rx) + (isbg ? 0 : 1)];
        int base = isbg ? (2 * SNP2) : (2 * SNP2 + NS * NREC * NT);
        out_st(out, base + (s * NREC + r) * NT + (t - 1), val);
    }

    const int wid  = i >> 6;
    const int lane = i & 63;
    const int ip   = 60 * wid + lane - 2;              // pair index
    const bool inb   = (unsigned)ip < 222u;
    const bool owner = (lane >= 2) && (lane < 62) && inb;

    const int x0 = 2 * ip, x1 = x0 + 1;
    const float4 z4 = make_float4(0.f, 0.f, 0.f, 0.f);
    const float* wc = g_w[cur];

    float pbx0 = 0.f, pbx1 = 0.f, pax0 = 0.f, pax1 = 0.f;
    if (inb) {
        pbx0 = g_pb[x0]; pbx1 = g_pb[x1];
        pax0 = g_pa[x0]; pax1 = g_pa[x1];
    }
    const bool pxreg = (ip <= 11 || ip >= 210);

    if (!isframe) {
        // ---- interior: 6 rows per thread, 10 shared w-row loads ----
        const int idx0 = s * NP2 + y0 * NP + x0;
        float4 r0 = z4, r1 = z4, r2 = z4, r3 = z4, r4 = z4;
        float4 r5 = z4, r6 = z4, r7 = z4, r8 = z4, r9 = z4;
        if (inb) {
            r0 = *(const float4*)(wc + 2 * (idx0 - 2 * NP));
            r1 = *(const float4*)(wc + 2 * (idx0 - NP));
            r2 = *(const float4*)(wc + 2 * idx0);
            r3 = *(const float4*)(wc + 2 * (idx0 + NP));
            r4 = *(const float4*)(wc + 2 * (idx0 + 2 * NP));
            r5 = *(const float4*)(wc + 2 * (idx0 + 3 * NP));
            r6 = *(const float4*)(wc + 2 * (idx0 + 4 * NP));
            r7 = *(const float4*)(wc + 2 * (idx0 + 5 * NP));
            r8 = *(const float4*)(wc + 2 * (idx0 + 6 * NP));
            r9 = *(const float4*)(wc + 2 * (idx0 + 7 * NP));
        }
        row_interior(t, s, y0,     ip, inb, owner, pxreg, pbx0, pbx1, pax0, pax1,
                     r0, r1, r2, r3, r4, cur, nxt);
        row_interior(t, s, y0 + 1, ip, inb, owner, pxreg, pbx0, pbx1, pax0, pax1,
                     r1, r2, r3, r4, r5, cur, nxt);
        row_interior(t, s, y0 + 2, ip, inb, owner, pxreg, pbx0, pbx1, pax0, pax1,
                     r2, r3, r4, r5, r6, cur, nxt);
        row_interior(t, s, y0 + 3, ip, inb, owner, pxreg, pbx0, pbx1, pax0, pax1,
                     r3, r4, r5, r6, r7, cur, nxt);
        row_interior(t, s, y0 + 4, ip, inb, owner, pxreg, pbx0, pbx1, pax0, pax1,
                     r4, r5, r6, r7, r8, cur, nxt);
        row_interior(t, s, y0 + 5, ip, inb, owner, pxreg, pbx0, pbx1, pax0, pax1,
                     r5, r6, r7, r8, r9, cur, nxt);
        return;
    }

    // ---- frame: R23/R19 single-row body (yframe always true here) ----
    const int y = y0;
    const int yx  = y * NP + x0;
    const int idx = s * NP2 + yx;

    float4 w4 = z4;
    if (inb) w4 = *(const float4*)(wc + 2 * idx);

    float4 wl = shup4(w4);
    float4 wr = shdn4(w4);

    float d2x_b0 = 0.f, d2x_b1 = 0.f, d2x_s0 = 0.f, d2x_s1 = 0.f;
    float4 pxn = z4;
    if (inb) {
        d2x_b0 = (C2A * (wl.x + wr.x) + C2B * (wl.z + w4.z) + C2C * w4.x) * INVH2;
        d2x_s0 = (C2A * (wl.y + wr.y) + C2B * (wl.w + w4.w) + C2C * w4.y) * INVH2;
        d2x_b1 = (C2A * (wl.z + wr.z) + C2B * (w4.x + wr.x) + C2C * w4.z) * INVH2;
        d2x_s1 = (C2A * (wl.w + wr.w) + C2B * (w4.y + wr.y) + C2C * w4.w) * INVH2;
        if (pxreg && pbx0 != 0.f) {
            float4 pxo = *(const float4*)(g_px[cur] + 2 * idx);
            float dwb0 = (C1A * wl.x - C1B * wl.z + C1B * w4.z - C1A * wr.x) * INVH;
            float dws0 = (C1A * wl.y - C1B * wl.w + C1B * w4.w - C1A * wr.y) * INVH;
            float dwb1 = (C1A * wl.z - C1B * w4.x + C1B * wr.x - C1A * wr.z) * INVH;
            float dws1 = (C1A * wl.w - C1B * w4.y + C1B * wr.y - C1A * wr.w) * INVH;
            pxn.x = pax0 * pxo.x + pbx0 * dwb0;
            pxn.y = pax0 * pxo.y + pbx0 * dws0;
            pxn.z = pax1 * pxo.z + pbx1 * dwb1;
            pxn.w = pax1 * pxo.w + pbx1 * dws1;
            if (owner)
                *(float4*)(g_px[nxt] + 2 * idx) = pxn;
        }
    }

    float dpx_b0 = 0.f, dpx_b1 = 0.f, dpx_s0 = 0.f, dpx_s1 = 0.f;
    {
        float4 pl = shup4(pxn);
        float4 pr = shdn4(pxn);
        if (pxreg) {
            dpx_b0 = (C1A * pl.x - C1B * pl.z + C1B * pxn.z - C1A * pr.x) * INVH;
            dpx_s0 = (C1A * pl.y - C1B * pl.w + C1B * pxn.w - C1A * pr.y) * INVH;
            dpx_b1 = (C1A * pl.z - C1B * pxn.x + C1B * pr.x - C1A * pr.z) * INVH;
            dpx_s1 = (C1A * pl.w - C1B * pxn.y + C1B * pr.y - C1A * pr.w) * INVH;
        }
    }
    if (!owner) return;

    const float pby = g_pb[y];
    float d2y_b0, d2y_b1, d2y_s0, d2y_s1;
    float dpy_b0 = 0.f, dpy_b1 = 0.f, dpy_s0 = 0.f, dpy_s1 = 0.f;
    {
        float4 wy[9];                        // rows y-4..y+4
        #pragma unroll
        for (int kk = 0; kk < 9; ++kk)
            wy[kk] = (kk == 4) ? w4 : ld4(wc, s, y - 4 + kk, ip);
        d2y_b0 = (C2A * (wy[2].x + wy[6].x) + C2B * (wy[3].x + wy[5].x) + C2C * wy[4].x) * INVH2;
        d2y_s0 = (C2A * (wy[2].y + wy[6].y) + C2B * (wy[3].y + wy[5].y) + C2C * wy[4].y) * INVH2;
        d2y_b1 = (C2A * (wy[2].z + wy[6].z) + C2B * (wy[3].z + wy[5].z) + C2C * wy[4].z) * INVH2;
        d2y_s1 = (C2A * (wy[2].w + wy[6].w) + C2B * (wy[3].w + wy[5].w) + C2C * wy[4].w) * INVH2;
        float4 pn[5];                        // psi_y_new rows y-2..y+2
        #pragma unroll
        for (int kk = 0; kk < 5; ++kk) {
            int yy = y - 2 + kk;
            float pbv = ((unsigned)yy < (unsigned)NP) ? g_pb[yy] : 0.f;  // uniform
            float4 r = z4;
            if (pbv != 0.f) {
                float pav = g_pa[yy];
                float4 po = *(const float4*)(g_py[cur] + 2 * (s * NP2 + yy * NP + x0));
                float db0 = (C1A * wy[kk].x - C1B * wy[kk+1].x + C1B * wy[kk+3].x - C1A * wy[kk+4].x) * INVH;
                float ds0 = (C1A * wy[kk].y - C1B * wy[kk+1].y + C1B * wy[kk+3].y - C1A * wy[kk+4].y) * INVH;
                float db1 = (C1A * wy[kk].z - C1B * wy[kk+1].z + C1B * wy[kk+3].z - C1A * wy[kk+4].z) * INVH;
                float ds1 = (C1A * wy[kk].w - C1B * wy[kk+1].w + C1B * wy[kk+3].w - C1A * wy[kk+4].w) * INVH;
                r.x = pav * po.x + pbv * db0;  r.y = pav * po.y + pbv * ds0;
                r.z = pav * po.z + pbv * db1;  r.w = pav * po.w + pbv * ds1;
            }
            pn[kk] = r;
        }
        dpy_b0 = (C1A * pn[0].x - C1B * pn[1].x + C1B * pn[3].x - C1A * pn[4].x) * INVH;
        dpy_s0 = (C1A * pn[0].y - C1B * pn[1].y + C1B * pn[3].y - C1A * pn[4].y) * INVH;
        dpy_b1 = (C1A * pn[0].z - C1B * pn[1].z + C1B * pn[3].z - C1A * pn[4].z) * INVH;
        dpy_s1 = (C1A * pn[0].w - C1B * pn[1].w + C1B * pn[3].w - C1A * pn[4].w) * INVH;
        if (pby != 0.f)
            *(float4*)(g_py[nxt] + 2 * idx) = pn[2];
    }

    float zy_b0 = 0.f, zy_b1 = 0.f, zy_s0 = 0.f, zy_s1 = 0.f;
    float zx_b0 = 0.f, zx_b1 = 0.f, zx_s0 = 0.f, zx_s1 = 0.f;
    if (pby != 0.f) {
        float pay = g_pa[y];
        float4 zo = *(const float4*)(g_zy + 2 * idx);
        zy_b0 = pay * zo.x + pby * (d2y_b0 + dpy_b0);
        zy_s0 = pay * zo.y + pby * (d2y_s0 + dpy_s0);
        zy_b1 = pay * zo.z + pby * (d2y_b1 + dpy_b1);
        zy_s1 = pay * zo.w + pby * (d2y_s1 + dpy_s1);
        *(float4*)(g_zy + 2 * idx) = make_float4(zy_b0, zy_s0, zy_b1, zy_s1);
    }
    if (pbx0 != 0.f) {
        float4 zo = *(const float4*)(g_zx + 2 * idx);
        zx_b0 = pax0 * zo.x + pbx0 * (d2x_b0 + dpx_b0);
        zx_s0 = pax0 * zo.y + pbx0 * (d2x_s0 + dpx_s0);
        zx_b1 = pax1 * zo.z + pbx1 * (d2x_b1 + dpx_b1);
        zx_s1 = pax1 * zo.w + pbx1 * (d2x_s1 + dpx_s1);
        *(float4*)(g_zx + 2 * idx) = make_float4(zx_b0, zx_s0, zx_b1, zx_s1);
    }

    float4 vb   = *(const float4*)(g_vb + 2 * yx);
    float4 prev = *(const float4*)(g_w[nxt] + 2 * idx);
    float lap_b0 = d2y_b0 + d2x_b0 + dpy_b0 + dpx_b0 + zy_b0 + zx_b0;
    float lap_s0 = d2y_s0 + d2x_s0 + dpy_s0 + dpx_s0 + zy_s0 + zx_s0;
    float lap_b1 = d2y_b1 + d2x_b1 + dpy_b1 + dpx_b1 + zy_b1 + zx_b1;
    float lap_s1 = d2y_s1 + d2x_s1 + dpy_s1 + dpx_s1 + zy_s1 + zx_s1;
    float wn_b0 = vb.x * lap_b0 + 2.f * w4.x - prev.x;
    float wn_s0 = vb.x * lap_s0 + 2.f * w4.y - prev.y + vb.y * lap_b0;
    float wn_b1 = vb.z * lap_b1 + 2.f * w4.z - prev.z;
    float wn_s1 = vb.z * lap_s1 + 2.f * w4.w - prev.w + vb.w * lap_b1;
    if (y == g_spos[2 * s]) {
        int sx = g_spos[2 * s + 1];
        if (sx == x0)      { wn_b0 += g_fbg[t * NS + s]; wn_s0 += g_fsc[t * NS + s]; }
        else if (sx == x1) { wn_b1 += g_fbg[t * NS + s]; wn_s1 += g_fsc[t * NS + s]; }
    }
    *(float4*)(g_w[nxt] + 2 * idx) = make_float4(wn_b0, wn_s0, wn_b1, wn_s1);
}

__global__ void finalize(const int* __restrict__ rloc, const int* __restrict__ rbloc,
                         void* __restrict__ out) {
    int i = blockIdx.x * blockDim.x + threadIdx.x;
    const float* w0 = g_w[0];     // NT even: newest field in buffer 0
    if (i < SNP2) {
        out_st(out, i,        w0[2 * i]);       // bg flat
        out_st(out, SNP2 + i, w0[2 * i + 1]);   // scattered flat
    }
    if (i < 2 * NS * NREC) {      // record last step (t = NT-1)
        bool isbg = i < NS * NREC;
        int k = isbg ? i : i - NS * NREC;
        int s = k / NREC, r = k % NREC;
        const int* rl = isbg ? rbloc : rloc;
        int ry = clampi(rl[(s * NREC + r) * 2 + 0], 0, NYX - 1) + PAD;
        int rx = clampi(rl[(s * NREC + r) * 2 + 1], 0, NYX - 1) + PAD;
        float val = w0[2 * (s * NP2 + ry * NP + rx) + (isbg ? 0 : 1)];
        int base = isbg ? (2 * SNP2) : (2 * SNP2 + NS * NREC * NT);
        out_st(out, base + (s * NREC + r) * NT + (NT - 1), val);
    }
}

extern "C" void kernel_launch(void* const* d_in, const int* in_sizes, int n_in,
                              void* d_out, int out_size, void* d_ws, size_t ws_size,
                              hipStream_t stream) {
    const void* v   = d_in[0];
    const void* sc  = d_in[1];
    const void* amp = d_in[2];
    const int* sloc  = (const int*)d_in[3];
    const int* rloc  = (const int*)d_in[4];
    const int* rbloc = (const int*)d_in[5];

    detect_mode<<<1, 64, 0, stream>>>(v);
    zero_state<<<(SNP2 / 2 + 255) / 256, 256, 0, stream>>>();
    prep_pad<<<(NP2 + 255) / 256, 256, 0, stream>>>(v, sc);
    prep_src<<<(NT * NS + 255) / 256, 256, 0, stream>>>(amp, sloc, v, sc);

    for (int t = 0; t < NT; ++t)
        step_fused<<<NBLK, 256, 0, stream>>>(t, rloc, rbloc, d_out);

    finalize<<<(SNP2 + 255) / 256, 256, 0, stream>>>(rloc, rbloc, d_out);
}

// Round 13
// 2092.654 us; speedup vs baseline: 1.3397x; 1.3397x over previous
//
#include <hip/hip_runtime.h>
#include <hip/hip_bf16.h>

// ScalarBorn: 4th-order FD scalar wave + Born scattering with CPML, MI355X.
// R27 = exact revert to R25 (2078us session best). R26 (6-row interior,
// bounds(256,2)) FALSIFIED at +35%: TLP cliff -- 1.78 waves/SIMD cannot hide
// latency, in-thread ILP does not substitute for waves. TLP floor is between
// 1.78 (fails) and 2.8 waves/SIMD (works). With traffic elasticity ~0.2
// (R25) and the ledger below, the lever inventory is empty; this structure
// is at its compute + per-launch-overhead floor (~6.9us/step).
// Kept: XCD banding (R15 -33%), one-round (R18 -7%), shuffle x-exchange /
// no LDS / no barriers (R19 -2%), interior 2-row (R23 -9%) + 3-row (R25 -2%).
// Falsified: 6-row interior (R26 +35%), 2-row frame merge (R24 +9%),
// 512-thr 2-row cap64 (R22 +19%), direct-load x-exch (R21 +54%),
// declustering (R20 +5%), full hoist (R16 +19%), cheap hoist (R17 +5%),
// aggregation (R8/R10), barrier removal w/ LDS (R12/R13), load cuts (R7),
// grid.sync (R4).

constexpr int NYX  = 400;
constexpr int NS   = 4;
constexpr int NREC = 100;
constexpr int NT   = 300;
constexpr int PAD  = 22;
constexpr int NP   = 444;
constexpr int NP2  = NP * NP;          // 197136
constexpr int SNP2 = NS * NP2;         // 788544
constexpr int NBLK = 720;              // 8 half-bands x (24 frame + 66 int3)
constexpr float DT    = 0.0005f;
constexpr float INVH  = 0.2f;
constexpr float INVH2 = 0.04f;
constexpr float C1A = 1.0f / 12.0f;
constexpr float C1B = 2.0f / 3.0f;
constexpr float C2A = -1.0f / 12.0f;
constexpr float C2B = 4.0f / 3.0f;
constexpr float C2C = -2.5f;

// interleaved state: element (b,s) pair for grid index idx lives at [2*idx, 2*idx+1]
__device__ __align__(16) float g_w[2][2 * SNP2];   // wavefield ping-pong
__device__ __align__(16) float g_px[2][2 * SNP2];  // psi_x dbuf
__device__ __align__(16) float g_py[2][2 * SNP2];  // psi_y dbuf
__device__ __align__(16) float g_zx[2 * SNP2];     // zeta_x
__device__ __align__(16) float g_zy[2 * SNP2];     // zeta_y
__device__ __align__(16) float g_vb[2 * NP2];      // (v2dt2, bscale) pairs
__device__ float g_pa[NP];
__device__ float g_pb[NP];
__device__ float g_fbg[NT * NS];
__device__ float g_fsc[NT * NS];
__device__ int   g_spos[2 * NS];
__device__ int   g_mode;               // 1 = bf16 io, 0 = f32 io

__device__ __forceinline__ int clampi(int v, int lo, int hi) {
    return v < lo ? lo : (v > hi ? hi : v);
}
__device__ __forceinline__ float in_ld(const void* p, int i) {
    if (g_mode) return __bfloat162float(((const __hip_bfloat16*)p)[i]);
    return ((const float*)p)[i];
}
__device__ __forceinline__ void out_st(void* p, int i, float v) {
    if (g_mode) ((__hip_bfloat16*)p)[i] = __float2bfloat16(v);
    else        ((float*)p)[i] = v;
}
// float4 = (b0,s0,b1,s1) at row yy, col pair ip of shot s; 0 if row OOB
__device__ __forceinline__ float4 ld4(const float* w, int s, int yy, int ip) {
    if ((unsigned)yy >= (unsigned)NP) return make_float4(0.f, 0.f, 0.f, 0.f);
    return *(const float4*)(w + 2 * (s * NP2 + yy * NP + 2 * ip));
}
__device__ __forceinline__ float4 shup4(float4 v) {
    return make_float4(__shfl_up(v.x, 1), __shfl_up(v.y, 1),
                       __shfl_up(v.z, 1), __shfl_up(v.w, 1));
}
__device__ __forceinline__ float4 shdn4(float4 v) {
    return make_float4(__shfl_down(v.x, 1), __shfl_down(v.y, 1),
                       __shfl_down(v.z, 1), __shfl_down(v.w, 1));
}

__global__ void detect_mode(const void* vptr) {
    if (threadIdx.x == 0 && blockIdx.x == 0) {
        const __hip_bfloat16* p = (const __hip_bfloat16*)vptr;
        int ok = 1;
        for (int i = 0; i < 32; i += 2) {
            float f = __bfloat162float(p[i]);
            if (!(f >= 1000.f && f <= 3000.f)) ok = 0;
        }
        g_mode = ok;
    }
}

__global__ void zero_state() {
    int i = blockIdx.x * blockDim.x + threadIdx.x;
    if (i >= SNP2 / 2) return;           // each array = 2*SNP2 floats = SNP2/2 float4
    float4 z = make_float4(0.f, 0.f, 0.f, 0.f);
    ((float4*)g_w[0])[i] = z;  ((float4*)g_w[1])[i] = z;
    ((float4*)g_px[0])[i] = z; ((float4*)g_px[1])[i] = z;
    ((float4*)g_py[0])[i] = z; ((float4*)g_py[1])[i] = z;
    ((float4*)g_zx)[i] = z;    ((float4*)g_zy)[i] = z;
}

__global__ void prep_pad(const void* __restrict__ v, const void* __restrict__ sc) {
    int i = blockIdx.x * blockDim.x + threadIdx.x;
    if (i >= NP2) return;
    int y = i / NP, x = i % NP;
    int vy = clampi(y - PAD, 0, NYX - 1);
    int vx = clampi(x - PAD, 0, NYX - 1);
    float vv = in_ld(v, vy * NYX + vx);
    float vd = vv * DT;
    float s = 0.f;
    if (y >= PAD && y < PAD + NYX && x >= PAD && x < PAD + NYX)
        s = in_ld(sc, (y - PAD) * NYX + (x - PAD));
    g_vb[2 * i]     = vd * vd;
    g_vb[2 * i + 1] = 2.f * vv * s * DT * DT;
    if (i < NP) {
        float fi = (float)i;
        float f1 = fminf(fmaxf((22.f - fi) * 0.05f, 0.f), 1.f);
        float f2 = fminf(fmaxf((fi - 421.f) * 0.05f, 0.f), 1.f);
        float frac = fmaxf(f1, f2);
        float sigma = 259.0408229f * frac * frac;
        const float alpha = 78.53981634f;
        float a = expf(-(sigma + alpha) * DT);
        g_pa[i] = a;
        g_pb[i] = (sigma > 0.f) ? sigma / (sigma + alpha) * (a - 1.f) : 0.f;
    }
}

__global__ void prep_src(const void* __restrict__ amp, const int* __restrict__ sloc,
                         const void* __restrict__ v, const void* __restrict__ sc) {
    int i = blockIdx.x * blockDim.x + threadIdx.x;
    if (i >= NT * NS) return;
    int s = i % NS, t = i / NS;
    int ly = clampi(sloc[s * 2 + 0], 0, NYX - 1);
    int lx = clampi(sloc[s * 2 + 1], 0, NYX - 1);
    float a  = in_ld(amp, s * NT + t);
    float vv = in_ld(v,  ly * NYX + lx);
    float ss = in_ld(sc, ly * NYX + lx);
    g_fbg[i] = -a * vv * vv * DT * DT;
    g_fsc[i] = -2.f * a * vv * ss * DT * DT;
    if (i < NS) {
        g_spos[2 * i]     = ly + PAD;
        g_spos[2 * i + 1] = lx + PAD;
    }
}

// Interior-row update (pb[y]==0 guaranteed: no psi_y/zeta_y/dpy).
// All lanes must call (shuffles inside); halo lanes exit after shuffles.
__device__ __forceinline__ void row_interior(
    int t, int s, int y, int ip, bool inb, bool owner, bool pxreg,
    float pbx0, float pbx1, float pax0, float pax1,
    float4 ym2, float4 ym1, float4 w4, float4 yp1, float4 yp2,
    int cur, int nxt)
{
    const int x0 = 2 * ip, x1 = x0 + 1;
    const int yx  = y * NP + x0;
    const int idx = s * NP2 + yx;
    const float4 z4 = make_float4(0.f, 0.f, 0.f, 0.f);

    float4 wl = shup4(w4);         // pair ip-1
    float4 wr = shdn4(w4);         // pair ip+1

    float d2x_b0 = 0.f, d2x_s0 = 0.f, d2x_b1 = 0.f, d2x_s1 = 0.f;
    float4 pxn = z4;
    if (inb) {
        d2x_b0 = (C2A * (wl.x + wr.x) + C2B * (wl.z + w4.z) + C2C * w4.x) * INVH2;
        d2x_s0 = (C2A * (wl.y + wr.y) + C2B * (wl.w + w4.w) + C2C * w4.y) * INVH2;
        d2x_b1 = (C2A * (wl.z + wr.z) + C2B * (w4.x + wr.x) + C2C * w4.z) * INVH2;
        d2x_s1 = (C2A * (wl.w + wr.w) + C2B * (w4.y + wr.y) + C2C * w4.w) * INVH2;
        if (pxreg && pbx0 != 0.f) {      // pb pair-uniform
            float4 pxo = *(const float4*)(g_px[cur] + 2 * idx);
            float dwb0 = (C1A * wl.x - C1B * wl.z + C1B * w4.z - C1A * wr.x) * INVH;
            float dws0 = (C1A * wl.y - C1B * wl.w + C1B * w4.w - C1A * wr.y) * INVH;
            float dwb1 = (C1A * wl.z - C1B * w4.x + C1B * wr.x - C1A * wr.z) * INVH;
            float dws1 = (C1A * wl.w - C1B * w4.y + C1B * wr.y - C1A * wr.w) * INVH;
            pxn.x = pax0 * pxo.x + pbx0 * dwb0;
            pxn.y = pax0 * pxo.y + pbx0 * dws0;
            pxn.z = pax1 * pxo.z + pbx1 * dwb1;
            pxn.w = pax1 * pxo.w + pbx1 * dws1;
            if (owner)
                *(float4*)(g_px[nxt] + 2 * idx) = pxn;
        }
    }

    float dpx_b0 = 0.f, dpx_s0 = 0.f, dpx_b1 = 0.f, dpx_s1 = 0.f;
    {
        float4 pl = shup4(pxn);
        float4 pr = shdn4(pxn);
        if (pxreg) {
            dpx_b0 = (C1A * pl.x - C1B * pl.z + C1B * pxn.z - C1A * pr.x) * INVH;
            dpx_s0 = (C1A * pl.y - C1B * pl.w + C1B * pxn.w - C1A * pr.y) * INVH;
            dpx_b1 = (C1A * pl.z - C1B * pxn.x + C1B * pr.x - C1A * pr.z) * INVH;
            dpx_s1 = (C1A * pl.w - C1B * pxn.y + C1B * pr.y - C1A * pr.w) * INVH;
        }
    }
    if (!owner) return;

    float d2y_b0 = (C2A * (ym2.x + yp2.x) + C2B * (ym1.x + yp1.x) + C2C * w4.x) * INVH2;
    float d2y_s0 = (C2A * (ym2.y + yp2.y) + C2B * (ym1.y + yp1.y) + C2C * w4.y) * INVH2;
    float d2y_b1 = (C2A * (ym2.z + yp2.z) + C2B * (ym1.z + yp1.z) + C2C * w4.z) * INVH2;
    float d2y_s1 = (C2A * (ym2.w + yp2.w) + C2B * (ym1.w + yp1.w) + C2C * w4.w) * INVH2;

    float zx_b0 = 0.f, zx_s0 = 0.f, zx_b1 = 0.f, zx_s1 = 0.f;
    if (pbx0 != 0.f) {
        float4 zo = *(const float4*)(g_zx + 2 * idx);
        zx_b0 = pax0 * zo.x + pbx0 * (d2x_b0 + dpx_b0);
        zx_s0 = pax0 * zo.y + pbx0 * (d2x_s0 + dpx_s0);
        zx_b1 = pax1 * zo.z + pbx1 * (d2x_b1 + dpx_b1);
        zx_s1 = pax1 * zo.w + pbx1 * (d2x_s1 + dpx_s1);
        *(float4*)(g_zx + 2 * idx) = make_float4(zx_b0, zx_s0, zx_b1, zx_s1);
    }

    float4 vb   = *(const float4*)(g_vb + 2 * yx);
    float4 prev = *(const float4*)(g_w[nxt] + 2 * idx);
    float lap_b0 = d2y_b0 + d2x_b0 + dpx_b0 + zx_b0;
    float lap_s0 = d2y_s0 + d2x_s0 + dpx_s0 + zx_s0;
    float lap_b1 = d2y_b1 + d2x_b1 + dpx_b1 + zx_b1;
    float lap_s1 = d2y_s1 + d2x_s1 + dpx_s1 + zx_s1;
    float wn_b0 = vb.x * lap_b0 + 2.f * w4.x - prev.x;
    float wn_s0 = vb.x * lap_s0 + 2.f * w4.y - prev.y + vb.y * lap_b0;
    float wn_b1 = vb.z * lap_b1 + 2.f * w4.z - prev.z;
    float wn_s1 = vb.z * lap_s1 + 2.f * w4.w - prev.w + vb.w * lap_b1;
    if (y == g_spos[2 * s]) {
        int sx = g_spos[2 * s + 1];
        if (sx == x0)      { wn_b0 += g_fbg[t * NS + s]; wn_s0 += g_fsc[t * NS + s]; }
        else if (sx == x1) { wn_b1 += g_fbg[t * NS + s]; wn_s1 += g_fsc[t * NS + s]; }
    }
    *(float4*)(g_w[nxt] + 2 * idx) = make_float4(wn_b0, wn_s0, wn_b1, wn_s1);
}

// one fused timestep. 720 blocks, 256 threads. Block map: xcd = bid&7 owns a
// 222-row half-band of shot s = xcd>>1 (half = xcd&1); k = bid>>3 in [0,90):
//   k < 24  -> FRAME block, one row y = half ? 420+k : k      (R23/R19 body)
//   k >= 24 -> INTERIOR block, rows y0..y0+2; y0 = (half?222:24)+3*(k-24)
// Within a row, R19 layout: wave w lane l -> pair ip = 60w+l-2, owners [2,62).
// Barrier-free, LDS-free; x-exchange via shuffles. bounds(256,5) -> <=102
// VGPR (R23 envelope), all 720 blocks resident -> one dispatch round.
__global__ void __launch_bounds__(256, 5)
step_fused(int t, const int* __restrict__ rloc, const int* __restrict__ rbloc,
           void* __restrict__ out) {
    const int i = threadIdx.x;
    const int bid = blockIdx.x;
    const int xcd = bid & 7;
    const int s = xcd >> 1;
    const int half = xcd & 1;
    const int k = bid >> 3;
    const int cur = t & 1, nxt = cur ^ 1;
    const bool isframe = (k < 24);
    const int y0 = isframe ? (half ? 420 + k : k)
                           : ((half ? 222 : 24) + 3 * (k - 24));

    if (t > 0 && isframe && y0 == 0 && i < 2 * NREC) {   // record step t-1
        int r = i % NREC;
        bool isbg = i < NREC;
        const int* rl = isbg ? rbloc : rloc;
        int ry = clampi(rl[(s * NREC + r) * 2 + 0], 0, NYX - 1) + PAD;
        int rx = clampi(rl[(s * NREC + r) * 2 + 1], 0, NYX - 1) + PAD;
        float val = g_w[cur][2 * (s * NP2 + ry * NP + rx) + (isbg ? 0 : 1)];
        int base = isbg ? (2 * SNP2) : (2 * SNP2 + NS * NREC * NT);
        out_st(out, base + (s * NREC + r) * NT + (t - 1), val);
    }

    const int wid  = i >> 6;
    const int lane = i & 63;
    const int ip   = 60 * wid + lane - 2;              // pair index
    const bool inb   = (unsigned)ip < 222u;
    const bool owner = (lane >= 2) && (lane < 62) && inb;

    const int x0 = 2 * ip, x1 = x0 + 1;
    const float4 z4 = make_float4(0.f, 0.f, 0.f, 0.f);
    const float* wc = g_w[cur];

    float pbx0 = 0.f, pbx1 = 0.f, pax0 = 0.f, pax1 = 0.f;
    if (inb) {
        pbx0 = g_pb[x0]; pbx1 = g_pb[x1];
        pax0 = g_pa[x0]; pax1 = g_pa[x1];
    }
    const bool pxreg = (ip <= 11 || ip >= 210);

    if (!isframe) {
        // ---- interior: 3 rows per thread, 7 shared w-row loads ----
        const int idx0 = s * NP2 + y0 * NP + x0;
        float4 r0 = z4, r1 = z4, r2 = z4, r3 = z4, r4 = z4, r5 = z4, r6 = z4;
        if (inb) {
            r0 = *(const float4*)(wc + 2 * (idx0 - 2 * NP));
            r1 = *(const float4*)(wc + 2 * (idx0 - NP));
            r2 = *(const float4*)(wc + 2 * idx0);
            r3 = *(const float4*)(wc + 2 * (idx0 + NP));
            r4 = *(const float4*)(wc + 2 * (idx0 + 2 * NP));
            r5 = *(const float4*)(wc + 2 * (idx0 + 3 * NP));
            r6 = *(const float4*)(wc + 2 * (idx0 + 4 * NP));
        }
        row_interior(t, s, y0,     ip, inb, owner, pxreg, pbx0, pbx1, pax0, pax1,
                     r0, r1, r2, r3, r4, cur, nxt);
        row_interior(t, s, y0 + 1, ip, inb, owner, pxreg, pbx0, pbx1, pax0, pax1,
                     r1, r2, r3, r4, r5, cur, nxt);
        row_interior(t, s, y0 + 2, ip, inb, owner, pxreg, pbx0, pbx1, pax0, pax1,
                     r2, r3, r4, r5, r6, cur, nxt);
        return;
    }

    // ---- frame: R23/R19 single-row body (yframe always true here) ----
    const int y = y0;
    const int yx  = y * NP + x0;
    const int idx = s * NP2 + yx;

    float4 w4 = z4;
    if (inb) w4 = *(const float4*)(wc + 2 * idx);

    float4 wl = shup4(w4);
    float4 wr = shdn4(w4);

    float d2x_b0 = 0.f, d2x_b1 = 0.f, d2x_s0 = 0.f, d2x_s1 = 0.f;
    float4 pxn = z4;
    if (inb) {
        d2x_b0 = (C2A * (wl.x + wr.x) + C2B * (wl.z + w4.z) + C2C * w4.x) * INVH2;
        d2x_s0 = (C2A * (wl.y + wr.y) + C2B * (wl.w + w4.w) + C2C * w4.y) * INVH2;
        d2x_b1 = (C2A * (wl.z + wr.z) + C2B * (w4.x + wr.x) + C2C * w4.z) * INVH2;
        d2x_s1 = (C2A * (wl.w + wr.w) + C2B * (w4.y + wr.y) + C2C * w4.w) * INVH2;
        if (pxreg && pbx0 != 0.f) {
            float4 pxo = *(const float4*)(g_px[cur] + 2 * idx);
            float dwb0 = (C1A * wl.x - C1B * wl.z + C1B * w4.z - C1A * wr.x) * INVH;
            float dws0 = (C1A * wl.y - C1B * wl.w + C1B * w4.w - C1A * wr.y) * INVH;
            float dwb1 = (C1A * wl.z - C1B * w4.x + C1B * wr.x - C1A * wr.z) * INVH;
            float dws1 = (C1A * wl.w - C1B * w4.y + C1B * wr.y - C1A * wr.w) * INVH;
            pxn.x = pax0 * pxo.x + pbx0 * dwb0;
            pxn.y = pax0 * pxo.y + pbx0 * dws0;
            pxn.z = pax1 * pxo.z + pbx1 * dwb1;
            pxn.w = pax1 * pxo.w + pbx1 * dws1;
            if (owner)
                *(float4*)(g_px[nxt] + 2 * idx) = pxn;
        }
    }

    float dpx_b0 = 0.f, dpx_b1 = 0.f, dpx_s0 = 0.f, dpx_s1 = 0.f;
    {
        float4 pl = shup4(pxn);
        float4 pr = shdn4(pxn);
        if (pxreg) {
            dpx_b0 = (C1A * pl.x - C1B * pl.z + C1B * pxn.z - C1A * pr.x) * INVH;
            dpx_s0 = (C1A * pl.y - C1B * pl.w + C1B * pxn.w - C1A * pr.y) * INVH;
            dpx_b1 = (C1A * pl.z - C1B * pxn.x + C1B * pr.x - C1A * pr.z) * INVH;
            dpx_s1 = (C1A * pl.w - C1B * pxn.y + C1B * pr.y - C1A * pr.w) * INVH;
        }
    }
    if (!owner) return;

    const float pby = g_pb[y];
    float d2y_b0, d2y_b1, d2y_s0, d2y_s1;
    float dpy_b0 = 0.f, dpy_b1 = 0.f, dpy_s0 = 0.f, dpy_s1 = 0.f;
    {
        float4 wy[9];                        // rows y-4..y+4
        #pragma unroll
        for (int kk = 0; kk < 9; ++kk)
            wy[kk] = (kk == 4) ? w4 : ld4(wc, s, y - 4 + kk, ip);
        d2y_b0 = (C2A * (wy[2].x + wy[6].x) + C2B * (wy[3].x + wy[5].x) + C2C * wy[4].x) * INVH2;
        d2y_s0 = (C2A * (wy[2].y + wy[6].y) + C2B * (wy[3].y + wy[5].y) + C2C * wy[4].y) * INVH2;
        d2y_b1 = (C2A * (wy[2].z + wy[6].z) + C2B * (wy[3].z + wy[5].z) + C2C * wy[4].z) * INVH2;
        d2y_s1 = (C2A * (wy[2].w + wy[6].w) + C2B * (wy[3].w + wy[5].w) + C2C * wy[4].w) * INVH2;
        float4 pn[5];                        // psi_y_new rows y-2..y+2
        #pragma unroll
        for (int kk = 0; kk < 5; ++kk) {
            int yy = y - 2 + kk;
            float pbv = ((unsigned)yy < (unsigned)NP) ? g_pb[yy] : 0.f;  // uniform
            float4 r = z4;
            if (pbv != 0.f) {
                float pav = g_pa[yy];
                float4 po = *(const float4*)(g_py[cur] + 2 * (s * NP2 + yy * NP + x0));
                float db0 = (C1A * wy[kk].x - C1B * wy[kk+1].x + C1B * wy[kk+3].x - C1A * wy[kk+4].x) * INVH;
                float ds0 = (C1A * wy[kk].y - C1B * wy[kk+1].y + C1B * wy[kk+3].y - C1A * wy[kk+4].y) * INVH;
                float db1 = (C1A * wy[kk].z - C1B * wy[kk+1].z + C1B * wy[kk+3].z - C1A * wy[kk+4].z) * INVH;
                float ds1 = (C1A * wy[kk].w - C1B * wy[kk+1].w + C1B * wy[kk+3].w - C1A * wy[kk+4].w) * INVH;
                r.x = pav * po.x + pbv * db0;  r.y = pav * po.y + pbv * ds0;
                r.z = pav * po.z + pbv * db1;  r.w = pav * po.w + pbv * ds1;
            }
            pn[kk] = r;
        }
        dpy_b0 = (C1A * pn[0].x - C1B * pn[1].x + C1B * pn[3].x - C1A * pn[4].x) * INVH;
        dpy_s0 = (C1A * pn[0].y - C1B * pn[1].y + C1B * pn[3].y - C1A * pn[4].y) * INVH;
        dpy_b1 = (C1A * pn[0].z - C1B * pn[1].z + C1B * pn[3].z - C1A * pn[4].z) * INVH;
        dpy_s1 = (C1A * pn[0].w - C1B * pn[1].w + C1B * pn[3].w - C1A * pn[4].w) * INVH;
        if (pby != 0.f)
            *(float4*)(g_py[nxt] + 2 * idx) = pn[2];
    }

    float zy_b0 = 0.f, zy_b1 = 0.f, zy_s0 = 0.f, zy_s1 = 0.f;
    float zx_b0 = 0.f, zx_b1 = 0.f, zx_s0 = 0.f, zx_s1 = 0.f;
    if (pby != 0.f) {
        float pay = g_pa[y];
        float4 zo = *(const float4*)(g_zy + 2 * idx);
        zy_b0 = pay * zo.x + pby * (d2y_b0 + dpy_b0);
        zy_s0 = pay * zo.y + pby * (d2y_s0 + dpy_s0);
        zy_b1 = pay * zo.z + pby * (d2y_b1 + dpy_b1);
        zy_s1 = pay * zo.w + pby * (d2y_s1 + dpy_s1);
        *(float4*)(g_zy + 2 * idx) = make_float4(zy_b0, zy_s0, zy_b1, zy_s1);
    }
    if (pbx0 != 0.f) {
        float4 zo = *(const float4*)(g_zx + 2 * idx);
        zx_b0 = pax0 * zo.x + pbx0 * (d2x_b0 + dpx_b0);
        zx_s0 = pax0 * zo.y + pbx0 * (d2x_s0 + dpx_s0);
        zx_b1 = pax1 * zo.z + pbx1 * (d2x_b1 + dpx_b1);
        zx_s1 = pax1 * zo.w + pbx1 * (d2x_s1 + dpx_s1);
        *(float4*)(g_zx + 2 * idx) = make_float4(zx_b0, zx_s0, zx_b1, zx_s1);
    }

    float4 vb   = *(const float4*)(g_vb + 2 * yx);
    float4 prev = *(const float4*)(g_w[nxt] + 2 * idx);
    float lap_b0 = d2y_b0 + d2x_b0 + dpy_b0 + dpx_b0 + zy_b0 + zx_b0;
    float lap_s0 = d2y_s0 + d2x_s0 + dpy_s0 + dpx_s0 + zy_s0 + zx_s0;
    float lap_b1 = d2y_b1 + d2x_b1 + dpy_b1 + dpx_b1 + zy_b1 + zx_b1;
    float lap_s1 = d2y_s1 + d2x_s1 + dpy_s1 + dpx_s1 + zy_s1 + zx_s1;
    float wn_b0 = vb.x * lap_b0 + 2.f * w4.x - prev.x;
    float wn_s0 = vb.x * lap_s0 + 2.f * w4.y - prev.y + vb.y * lap_b0;
    float wn_b1 = vb.z * lap_b1 + 2.f * w4.z - prev.z;
    float wn_s1 = vb.z * lap_s1 + 2.f * w4.w - prev.w + vb.w * lap_b1;
    if (y == g_spos[2 * s]) {
        int sx = g_spos[2 * s + 1];
        if (sx == x0)      { wn_b0 += g_fbg[t * NS + s]; wn_s0 += g_fsc[t * NS + s]; }
        else if (sx == x1) { wn_b1 += g_fbg[t * NS + s]; wn_s1 += g_fsc[t * NS + s]; }
    }
    *(float4*)(g_w[nxt] + 2 * idx) = make_float4(wn_b0, wn_s0, wn_b1, wn_s1);
}

__global__ void finalize(const int* __restrict__ rloc, const int* __restrict__ rbloc,
                         void* __restrict__ out) {
    int i = blockIdx.x * blockDim.x + threadIdx.x;
    const float* w0 = g_w[0];     // NT even: newest field in buffer 0
    if (i < SNP2) {
        out_st(out, i,        w0[2 * i]);       // bg flat
        out_st(out, SNP2 + i, w0[2 * i + 1]);   // scattered flat
    }
    if (i < 2 * NS * NREC) {      // record last step (t = NT-1)
        bool isbg = i < NS * NREC;
        int k = isbg ? i : i - NS * NREC;
        int s = k / NREC, r = k % NREC;
        const int* rl = isbg ? rbloc : rloc;
        int ry = clampi(rl[(s * NREC + r) * 2 + 0], 0, NYX - 1) + PAD;
        int rx = clampi(rl[(s * NREC + r) * 2 + 1], 0, NYX - 1) + PAD;
        float val = w0[2 * (s * NP2 + ry * NP + rx) + (isbg ? 0 : 1)];
        int base = isbg ? (2 * SNP2) : (2 * SNP2 + NS * NREC * NT);
        out_st(out, base + (s * NREC + r) * NT + (NT - 1), val);
    }
}

extern "C" void kernel_launch(void* const* d_in, const int* in_sizes, int n_in,
                              void* d_out, int out_size, void* d_ws, size_t ws_size,
                              hipStream_t stream) {
    const void* v   = d_in[0];
    const void* sc  = d_in[1];
    const void* amp = d_in[2];
    const int* sloc  = (const int*)d_in[3];
    const int* rloc  = (const int*)d_in[4];
    const int* rbloc = (const int*)d_in[5];

    detect_mode<<<1, 64, 0, stream>>>(v);
    zero_state<<<(SNP2 / 2 + 255) / 256, 256, 0, stream>>>();
    prep_pad<<<(NP2 + 255) / 256, 256, 0, stream>>>(v, sc);
    prep_src<<<(NT * NS + 255) / 256, 256, 0, stream>>>(amp, sloc, v, sc);

    for (int t = 0; t < NT; ++t)
        step_fused<<<NBLK, 256, 0, stream>>>(t, rloc, rbloc, d_out);

    finalize<<<(SNP2 + 255) / 256, 256, 0, stream>>>(rloc, rbloc, d_out);
}